// Round 1
// baseline (5020.217 us; speedup 1.0000x reference)
//
#include <hip/hip_runtime.h>

// Problem constants (from reference setup_inputs)
#define B_   16
#define T_   2048
#define D_   512
#define C_   1024
#define Q_   8
#define M_   (B_ * T_)      // 32768 rows
#define ND_  (M_ * D_)      // 16777216 elements

static constexpr float BETA = 0.25f;

// ---------------------------------------------------------------------------
// Zero the quantized-output accumulator region of d_out and the loss scalar.
// Must run every call: harness poisons d_out with 0xAA and we accumulate.
// ---------------------------------------------------------------------------
__global__ __launch_bounds__(256) void k_init(float* __restrict__ qout,
                                              float* __restrict__ loss) {
    const size_t tid = (size_t)blockIdx.x * blockDim.x + threadIdx.x;
    float4* q4 = (float4*)qout;
    const size_t n4 = ND_ / 4;
    for (size_t i = tid; i < n4; i += (size_t)gridDim.x * blockDim.x)
        q4[i] = make_float4(0.f, 0.f, 0.f, 0.f);
    if (tid == 0) *loss = 0.f;
}

// ---------------------------------------------------------------------------
// Precompute ||e_c||^2 for all Q*C codes. One wave per code.
// ---------------------------------------------------------------------------
__global__ __launch_bounds__(256) void k_enorm(const float* __restrict__ cb,
                                               float* __restrict__ enorm) {
    const int wave = threadIdx.x >> 6;
    const int lane = threadIdx.x & 63;
    const int code = blockIdx.x * 4 + wave;   // 0 .. Q_*C_-1
    const float4* row = (const float4*)(cb + (size_t)code * D_);
    float s = 0.f;
    #pragma unroll
    for (int k = 0; k < 2; ++k) {             // 128 float4 per row, 2 per lane
        float4 v = row[lane + k * 64];
        s += v.x * v.x + v.y * v.y + v.z * v.z + v.w * v.w;
    }
    #pragma unroll
    for (int m = 32; m; m >>= 1) s += __shfl_xor(s, m);
    if (lane == 0) enorm[code] = s;
}

// ---------------------------------------------------------------------------
// One RVQ stage, fully fused:
//   residual r = x - qout  (recomputed on the fly; never materialized)
//   score(r,c) = ||e_c||^2 - 2 r.e_c    (||r||^2 constant per row -> dropped)
//   idx = argmin_c score   (ascending scan + strict < == jnp.argmin tie rule)
//   qout += e[idx];  loss += BETA * mean((x - qout_new)^2)
// Block: 256 threads, 64 rows x (16 chunks of 64 codes), 4x4 reg accumulators.
// ---------------------------------------------------------------------------
__global__ __launch_bounds__(256) void k_stage(const float* __restrict__ x,
                                               const float* __restrict__ cb,
                                               const float* __restrict__ enorm,
                                               float* __restrict__ qout,
                                               float* __restrict__ idxf,
                                               float* __restrict__ loss) {
    __shared__ float As[16][68];   // [k][row], pad 68 (17 float4) keeps 16B align
    __shared__ float Bs[16][68];   // [k][code_local]
    __shared__ int   sidx[64];
    __shared__ float red[4];

    const int tid = threadIdx.x;
    const int ty  = tid >> 4;          // 0..15 -> rows ty*4..ty*4+3
    const int tx  = tid & 15;          // 0..15 -> local cols tx*4..tx*4+3
    const int rbase = blockIdx.x * 64;

    // tile-load mapping: one float4 per thread per operand
    const int lrow = tid >> 2;         // 0..63
    const int ld4  = tid & 3;          // 0..3  (which float4 along k)

    float minv[4];
    int   mini[4];
    #pragma unroll
    for (int i = 0; i < 4; ++i) { minv[i] = 3.4e38f; mini[i] = 0; }

    for (int cchunk = 0; cchunk < 16; ++cchunk) {
        const int cbase = cchunk * 64;
        float acc[4][4] = {};

        for (int kb = 0; kb < D_; kb += 16) {
            __syncthreads();   // protect LDS from previous iteration's readers
            {
                const size_t g = (size_t)(rbase + lrow) * D_ + kb + ld4 * 4;
                const float4 xv = *(const float4*)(x + g);
                const float4 qv = *(const float4*)(qout + g);
                As[ld4 * 4 + 0][lrow] = xv.x - qv.x;
                As[ld4 * 4 + 1][lrow] = xv.y - qv.y;
                As[ld4 * 4 + 2][lrow] = xv.z - qv.z;
                As[ld4 * 4 + 3][lrow] = xv.w - qv.w;
                const size_t gb = (size_t)(cbase + lrow) * D_ + kb + ld4 * 4;
                const float4 bv = *(const float4*)(cb + gb);
                Bs[ld4 * 4 + 0][lrow] = bv.x;
                Bs[ld4 * 4 + 1][lrow] = bv.y;
                Bs[ld4 * 4 + 2][lrow] = bv.z;
                Bs[ld4 * 4 + 3][lrow] = bv.w;
            }
            __syncthreads();

            #pragma unroll
            for (int kk = 0; kk < 16; ++kk) {
                const float4 av = *(const float4*)&As[kk][ty * 4];
                const float4 bv = *(const float4*)&Bs[kk][tx * 4];
                const float a[4] = {av.x, av.y, av.z, av.w};
                const float b[4] = {bv.x, bv.y, bv.z, bv.w};
                #pragma unroll
                for (int i = 0; i < 4; ++i)
                    #pragma unroll
                    for (int j = 0; j < 4; ++j)
                        acc[i][j] = fmaf(a[i], b[j], acc[i][j]);
            }
        }

        // merge this chunk into the running per-thread argmin
        #pragma unroll
        for (int j = 0; j < 4; ++j) {
            const int c = cbase + tx * 4 + j;
            const float en = enorm[c];
            #pragma unroll
            for (int i = 0; i < 4; ++i) {
                const float s = fmaf(-2.f, acc[i][j], en);
                if (s < minv[i]) { minv[i] = s; mini[i] = c; }  // strict: keep lowest c
            }
        }
    }

    // reduce argmin across the 16 lanes sharing each row (tie -> lower index)
    #pragma unroll
    for (int i = 0; i < 4; ++i) {
        float v = minv[i];
        int  id = mini[i];
        #pragma unroll
        for (int m = 1; m < 16; m <<= 1) {
            const float ov = __shfl_xor(v, m);
            const int  oid = __shfl_xor(id, m);
            if (ov < v || (ov == v && oid < id)) { v = ov; id = oid; }
        }
        if (tx == 0) sidx[ty * 4 + i] = id;
    }
    __syncthreads();

    // write indices (as float values; d_out is read back as float32)
    if (tid < 64) idxf[rbase + tid] = (float)sidx[tid];

    // fused update: qout += e[idx]; loss partial = sum((x - qout_new)^2)
    float lsum = 0.f;
    #pragma unroll 4
    for (int k = 0; k < 32; ++k) {
        const int fidx = tid + k * 256;     // 0..8191 float4 slots
        const int row  = fidx >> 7;         // 0..63
        const int c4   = fidx & 127;        // float4 within row
        const int code = sidx[row];
        const float4 qv = *(const float4*)(cb + (size_t)code * D_ + c4 * 4);
        const size_t g  = (size_t)(rbase + row) * D_ + c4 * 4;
        const float4 xv = *(const float4*)(x + g);
        const float4 ov = *(const float4*)(qout + g);
        const float4 nq = make_float4(ov.x + qv.x, ov.y + qv.y,
                                      ov.z + qv.z, ov.w + qv.w);
        *(float4*)(qout + g) = nq;
        const float rx = xv.x - nq.x, ry = xv.y - nq.y;
        const float rz = xv.z - nq.z, rw = xv.w - nq.w;
        lsum += rx * rx + ry * ry + rz * rz + rw * rw;
    }
    #pragma unroll
    for (int m = 32; m; m >>= 1) lsum += __shfl_xor(lsum, m);
    if ((tid & 63) == 0) red[tid >> 6] = lsum;
    __syncthreads();
    if (tid == 0) {
        const float s = red[0] + red[1] + red[2] + red[3];
        atomicAdd(loss, s * (BETA / (float)ND_));
    }
}

// ---------------------------------------------------------------------------
extern "C" void kernel_launch(void* const* d_in, const int* in_sizes, int n_in,
                              void* d_out, int out_size, void* d_ws, size_t ws_size,
                              hipStream_t stream) {
    const float* x  = (const float*)d_in[0];   // [16,2048,512]
    const float* cb = (const float*)d_in[1];   // [8,1024,512]

    float* out   = (float*)d_out;
    float* qout  = out;                              // 16777216 floats
    float* idxf  = out + (size_t)ND_;                // 262144 floats (indices)
    float* loss  = out + (size_t)ND_ + (size_t)Q_ * M_;  // 1 float
    float* enorm = (float*)d_ws;                     // 8192 floats

    hipLaunchKernelGGL(k_init, dim3(4096), dim3(256), 0, stream, qout, loss);
    hipLaunchKernelGGL(k_enorm, dim3((Q_ * C_) / 4), dim3(256), 0, stream, cb, enorm);

    for (int q = 0; q < Q_; ++q) {
        hipLaunchKernelGGL(k_stage, dim3(M_ / 64), dim3(256), 0, stream,
                           x,
                           cb + (size_t)q * C_ * D_,
                           enorm + (size_t)q * C_,
                           qout,
                           idxf + (size_t)q * M_,
                           loss);
    }
}

// Round 2
// 3171.034 us; speedup vs baseline: 1.5831x; 1.5831x over previous
//
#include <hip/hip_runtime.h>

// Problem constants
#define B_   16
#define T_   2048
#define D_   512
#define C_   1024
#define Q_   8
#define M_   (B_ * T_)      // 32768 rows
#define ND_  (M_ * D_)      // 16777216 elements

static constexpr float BETA = 0.25f;
static constexpr float MARGIN2 = 1.0f;   // 2*tau certification margin (approx-score units)

typedef short  short8v __attribute__((ext_vector_type(8)));
typedef short  short4v __attribute__((ext_vector_type(4)));
typedef float  f32x4   __attribute__((ext_vector_type(4)));

// ws layout (fast path)
#define WS_CB16   0u                      // 4194304 bf16 = 8388608 B
#define WS_ENORM  8388608u                // 8192 f32
#define WS_IDXI   8421376u                // 32768 int
#define WS_FLAGS  8552448u                // 32768 int
#define WS_CNT    8683520u                // 8 int
#define WS_NEED   8683552u

__device__ __forceinline__ short f2bf(float f) {
    unsigned u = __float_as_uint(f);
    u += 0x7fffu + ((u >> 16) & 1u);      // RNE to bf16
    return (short)(u >> 16);
}

// ===========================================================================
// Shared helpers
// ===========================================================================
__global__ __launch_bounds__(256) void k_enorm(const float* __restrict__ cb,
                                               float* __restrict__ enorm) {
    const int wave = threadIdx.x >> 6;
    const int lane = threadIdx.x & 63;
    const int code = blockIdx.x * 4 + wave;   // 0 .. Q_*C_-1
    const float4* row = (const float4*)(cb + (size_t)code * D_);
    float s = 0.f;
    #pragma unroll
    for (int k = 0; k < 2; ++k) {
        float4 v = row[lane + k * 64];
        s += v.x * v.x + v.y * v.y + v.z * v.z + v.w * v.w;
    }
    #pragma unroll
    for (int m = 32; m; m >>= 1) s += __shfl_xor(s, m);
    if (lane == 0) enorm[code] = s;
}

__global__ __launch_bounds__(256) void k_cvt(const float* __restrict__ cb,
                                             short* __restrict__ cb16) {
    const int i0 = (blockIdx.x * 256 + threadIdx.x) * 8;   // 4194304 total
    float4 a = *(const float4*)(cb + i0);
    float4 b = *(const float4*)(cb + i0 + 4);
    short8v s;
    s[0]=f2bf(a.x); s[1]=f2bf(a.y); s[2]=f2bf(a.z); s[3]=f2bf(a.w);
    s[4]=f2bf(b.x); s[5]=f2bf(b.y); s[6]=f2bf(b.z); s[7]=f2bf(b.w);
    *(short8v*)(cb16 + i0) = s;
}

__global__ __launch_bounds__(64) void k_zero(float* __restrict__ loss,
                                             int* __restrict__ cnt) {
    if (threadIdx.x == 0) *loss = 0.f;
    if (threadIdx.x < 8) cnt[threadIdx.x] = 0;
}

// ===========================================================================
// Fast path: fused stage kernel (update prev stage + bf16 MFMA scores + top2)
// Block: 512 threads, 128 rows, all 1024 codes. Grid 256 (exactly 1/CU).
// LDS: A[128][512] bf16 swizzled (131072) | B[256][40] bf16 (20480)
//      | merge mv1/mv2 f32[4][128], mi1 int[4][128] | red f32[8]
// ===========================================================================
#define SA_OFF   0
#define SB_OFF   131072
#define MV1_OFF  151552
#define MV2_OFF  153600
#define MI1_OFF  155648
#define RED_OFF  157696
#define SM_TOTAL 157728

__global__ __launch_bounds__(512, 2)
void k_approx(const float* __restrict__ x,
              const float* __restrict__ cbprev,   // fp32 codebook of stage q-1 (gather)
              const short* __restrict__ cb16q,    // bf16 codebook of stage q
              const float* __restrict__ enormq,   // enorm of stage q
              float* __restrict__ qout,
              int*   __restrict__ idxi,           // read prev stage, write cur
              float* __restrict__ idxf,           // tentative float indices (stage q)
              int*   __restrict__ flaglist,
              int*   __restrict__ cnt,
              float* __restrict__ loss,
              int q) {
    __shared__ __align__(16) char smem[SM_TOTAL];
    short* smA = (short*)(smem + SA_OFF);
    char*  smB = smem + SB_OFF;
    float* mv1 = (float*)(smem + MV1_OFF);
    float* mv2 = (float*)(smem + MV2_OFF);
    int*   mi1 = (int*)(smem + MI1_OFF);
    float* red = (float*)(smem + RED_OFF);

    const int tid  = threadIdx.x;
    const int bid  = blockIdx.x;
    const int lane = tid & 63;
    const int w    = tid >> 6;          // wave 0..7
    const int rh   = w >> 2;            // row half (0,1) -> rows rh*64..+63
    const int wc   = w & 3;             // code quarter within chunk
    const int h    = lane >> 4;         // 0..3
    const int lr   = lane & 15;         // 0..15
    const int rbase = bid * 128;

    // ---------------- phase 1: apply prev stage, build bf16 residual tile ----
    float lsum = 0.f;
    for (int i = 0; i < 32; ++i) {
        const int s   = tid + i * 512;        // 0..16383 float4 slots
        const int row = s >> 7;               // 0..127
        const int c4  = s & 127;
        const size_t g = (size_t)(rbase + row) * D_ + c4 * 4;
        const float4 xv = *(const float4*)(x + g);
        float4 r;
        if (q == 0) {
            r = xv;
        } else {
            const int code = idxi[rbase + row];
            const float4 ev = *(const float4*)(cbprev + (size_t)code * D_ + c4 * 4);
            float4 nq;
            if (q == 1) nq = ev;
            else {
                const float4 qv = *(const float4*)(qout + g);
                nq = make_float4(qv.x + ev.x, qv.y + ev.y, qv.z + ev.z, qv.w + ev.w);
            }
            *(float4*)(qout + g) = nq;
            r = make_float4(xv.x - nq.x, xv.y - nq.y, xv.z - nq.z, xv.w - nq.w);
            lsum += r.x * r.x + r.y * r.y + r.z * r.z + r.w * r.w;
        }
        short4v sv; sv[0]=f2bf(r.x); sv[1]=f2bf(r.y); sv[2]=f2bf(r.z); sv[3]=f2bf(r.w);
        int ab = (row << 10) + (c4 << 3);
        ab ^= ((row & 7) << 4);               // XOR swizzle (bank-conflict-free frag reads)
        *(short4v*)((char*)smA + ab) = sv;
    }
    __syncthreads();
    if (q != 0) {    // loss contribution of stage q-1
        #pragma unroll
        for (int m = 32; m; m >>= 1) lsum += __shfl_xor(lsum, m);
        if (lane == 0) red[w] = lsum;
        __syncthreads();
        if (tid == 0) {
            float t = 0.f;
            #pragma unroll
            for (int i = 0; i < 8; ++i) t += red[i];
            atomicAdd(loss, t * (BETA / (float)ND_));
        }
    }

    // ---------------- phase 2: bf16 MFMA scores + per-lane top2 -------------
    float v1[16], v2[16]; int i1[16];
    #pragma unroll
    for (int i = 0; i < 16; ++i) { v1[i] = 3.4e38f; v2[i] = 3.4e38f; i1[i] = 0; }

    f32x4 acc[4][4];
    // B staging: 1024 chunks of 16B per step; this thread's 2 chunks:
    const int ch0 = tid, ch1 = tid + 512;
    const int co0 = ch0 >> 2, ko0 = (ch0 & 3) * 8;
    const int co1 = ch1 >> 2, ko1 = (ch1 & 3) * 8;
    int4 pf0, pf1;
    {   // prefetch step 0 (cc=0, kb=0)
        pf0 = *(const int4*)(cb16q + (size_t)co0 * D_ + ko0);
        pf1 = *(const int4*)(cb16q + (size_t)co1 * D_ + ko1);
    }

    for (int s = 0; s < 64; ++s) {
        const int cc = s >> 4;            // code chunk 0..3 (256 codes each)
        const int kb = s & 15;            // k block 0..15 (K=32 each)
        if (kb == 0) {
            #pragma unroll
            for (int ri = 0; ri < 4; ++ri)
                #pragma unroll
                for (int cj = 0; cj < 4; ++cj)
                    acc[ri][cj] = (f32x4){0.f, 0.f, 0.f, 0.f};
        }
        __syncthreads();                  // previous step's readers done
        *(int4*)(smB + co0 * 80 + ko0 * 2) = pf0;
        *(int4*)(smB + co1 * 80 + ko1 * 2) = pf1;
        __syncthreads();                  // B tile visible
        if (s < 63) {                     // issue next-step loads (hidden under MFMA)
            const int nc = (s + 1) >> 4, nk = (s + 1) & 15;
            pf0 = *(const int4*)(cb16q + (size_t)(nc * 256 + co0) * D_ + nk * 32 + ko0);
            pf1 = *(const int4*)(cb16q + (size_t)(nc * 256 + co1) * D_ + nk * 32 + ko1);
        }
        // fragments
        const int kbyte = kb * 64 + h * 16;
        short8v a[4], b[4];
        #pragma unroll
        for (int ri = 0; ri < 4; ++ri) {
            const int row = rh * 64 + ri * 16 + lr;
            int off = (row << 10) + kbyte;
            off ^= ((row & 7) << 4);
            a[ri] = *(const short8v*)((const char*)smA + off);
        }
        #pragma unroll
        for (int cj = 0; cj < 4; ++cj) {
            const int codeL = wc * 64 + cj * 16 + lr;
            b[cj] = *(const short8v*)(smB + codeL * 80 + h * 16);
        }
        #pragma unroll
        for (int ri = 0; ri < 4; ++ri)
            #pragma unroll
            for (int cj = 0; cj < 4; ++cj)
                acc[ri][cj] = __builtin_amdgcn_mfma_f32_16x16x32_bf16(a[ri], b[cj], acc[ri][cj], 0, 0, 0);

        if (kb == 15) {   // fold this code chunk into running top2
            #pragma unroll
            for (int cj = 0; cj < 4; ++cj) {
                const int codeG = cc * 256 + wc * 64 + cj * 16 + lr;
                const float en = enormq[codeG];
                #pragma unroll
                for (int ri = 0; ri < 4; ++ri)
                    #pragma unroll
                    for (int rg = 0; rg < 4; ++rg) {
                        const float sv = fmaf(-2.f, acc[ri][cj][rg], en);
                        const int slot = ri * 4 + rg;
                        if (sv < v1[slot]) { v2[slot] = v1[slot]; v1[slot] = sv; i1[slot] = codeG; }
                        else               { v2[slot] = fminf(v2[slot], sv); }
                    }
            }
        }
    }

    // cross-lane merge (16 lanes share each row-slot group)
    #pragma unroll
    for (int slot = 0; slot < 16; ++slot) {
        float a1 = v1[slot], a2 = v2[slot]; int ai = i1[slot];
        #pragma unroll
        for (int m = 1; m < 16; m <<= 1) {
            const float b1 = __shfl_xor(a1, m);
            const int   bi = __shfl_xor(ai, m);
            const float b2 = __shfl_xor(a2, m);
            if (b1 < a1 || (b1 == a1 && bi < ai)) { a2 = fminf(a1, b2); a1 = b1; ai = bi; }
            else                                  { a2 = fminf(a2, b1); }
        }
        v1[slot] = a1; v2[slot] = a2; i1[slot] = ai;
    }
    if (lr == 0) {
        #pragma unroll
        for (int ri = 0; ri < 4; ++ri)
            #pragma unroll
            for (int rg = 0; rg < 4; ++rg) {
                const int row = rh * 64 + ri * 16 + h * 4 + rg;
                mv1[wc * 128 + row] = v1[ri * 4 + rg];
                mv2[wc * 128 + row] = v2[ri * 4 + rg];
                mi1[wc * 128 + row] = i1[ri * 4 + rg];
            }
    }
    __syncthreads();

    if (tid < 128) {
        const int row = tid;
        float V1 = mv1[row]; int I1 = mi1[row]; float V2 = mv2[row];
        #pragma unroll
        for (int k = 1; k < 4; ++k) {
            const float b1 = mv1[k * 128 + row];
            const int   bi = mi1[k * 128 + row];
            const float b2 = mv2[k * 128 + row];
            if (b1 < V1 || (b1 == V1 && bi < I1)) { V2 = fminf(V1, b2); V1 = b1; I1 = bi; }
            else                                  { V2 = fminf(V2, b1); }
        }
        const int grow = rbase + row;
        idxi[grow] = I1;
        idxf[grow] = (float)I1;
        if (!(V2 - V1 >= MARGIN2)) {
            const int p = atomicAdd(cnt, 1);
            flaglist[p] = grow;
        }
    }
}

// ===========================================================================
// Exact fp32 re-argmin for uncertified rows (8 rows per pass per block)
// ===========================================================================
#define XR 8
__global__ __launch_bounds__(256)
void k_exact(const float* __restrict__ x, const float* __restrict__ qout,
             const float* __restrict__ cbq, const float* __restrict__ enq,
             int* __restrict__ idxi, float* __restrict__ idxf,
             const int* __restrict__ flaglist, const int* __restrict__ cnt,
             int useq) {
    __shared__ float rr[XR][512];
    __shared__ int   rowid[XR];
    __shared__ float rn[XR];
    __shared__ float wv[4];
    __shared__ int   wi[4];
    const int tid = threadIdx.x;
    const int n = *cnt;
    for (int base = blockIdx.x * XR; base < n; base += gridDim.x * XR) {
        if (tid < XR) rowid[tid] = (base + tid < n) ? flaglist[base + tid] : -1;
        __syncthreads();
        for (int i = 0; i < 16; ++i) {
            const int s = tid + i * 256;
            const int j = s >> 9, k = s & 511;
            const int row = rowid[j];
            float v = 0.f;
            if (row >= 0) {
                v = x[(size_t)row * D_ + k];
                if (useq) v -= qout[(size_t)row * D_ + k];
            }
            rr[j][k] = v;
        }
        __syncthreads();
        if (tid < XR) {
            float s2 = 0.f;
            for (int k = 0; k < 512; ++k) s2 = fmaf(rr[tid][k], rr[tid][k], s2);
            rn[tid] = s2;
        }
        __syncthreads();

        float best[XR]; int bidx[XR];
        #pragma unroll
        for (int j = 0; j < XR; ++j) { best[j] = 3.4e38f; bidx[j] = 0; }
        for (int c0 = 0; c0 < 4; ++c0) {
            const int c = tid * 4 + c0;
            float dot[XR];
            #pragma unroll
            for (int j = 0; j < XR; ++j) dot[j] = 0.f;
            const float4* cbr = (const float4*)(cbq + (size_t)c * D_);
            for (int k4 = 0; k4 < 128; ++k4) {
                const float4 e = cbr[k4];
                #pragma unroll
                for (int j = 0; j < XR; ++j) {
                    const float4 rv = *(const float4*)&rr[j][k4 * 4];
                    dot[j] = fmaf(e.x, rv.x, fmaf(e.y, rv.y, fmaf(e.z, rv.z, fmaf(e.w, rv.w, dot[j]))));
                }
            }
            const float en = enq[c];
            #pragma unroll
            for (int j = 0; j < XR; ++j) {
                const float sc = rn[j] + en - 2.f * dot[j];
                if (sc < best[j]) { best[j] = sc; bidx[j] = c; }
            }
        }
        for (int j = 0; j < XR; ++j) {
            float v = best[j]; int id = bidx[j];
            #pragma unroll
            for (int m = 1; m < 64; m <<= 1) {
                const float ov = __shfl_xor(v, m);
                const int  oid = __shfl_xor(id, m);
                if (ov < v || (ov == v && oid < id)) { v = ov; id = oid; }
            }
            if ((tid & 63) == 0) { wv[tid >> 6] = v; wi[tid >> 6] = id; }
            __syncthreads();
            if (tid == 0 && rowid[j] >= 0) {
                float V = wv[0]; int I = wi[0];
                #pragma unroll
                for (int k = 1; k < 4; ++k)
                    if (wv[k] < V || (wv[k] == V && wi[k] < I)) { V = wv[k]; I = wi[k]; }
                idxi[rowid[j]] = I;
                idxf[rowid[j]] = (float)I;
            }
            __syncthreads();
        }
    }
}

// ===========================================================================
// Final update for stage 7 (+ its loss term)
// ===========================================================================
__global__ __launch_bounds__(256)
void k_final(const float* __restrict__ x, const float* __restrict__ cb7,
             const int* __restrict__ idxi, float* __restrict__ qout,
             float* __restrict__ loss) {
    __shared__ float red[4];
    const int tid = threadIdx.x;
    const int rbase = blockIdx.x * 64;
    float lsum = 0.f;
    for (int i = 0; i < 32; ++i) {
        const int s = tid + i * 256;
        const int row = s >> 7, c4 = s & 127;
        const int grow = rbase + row;
        const int code = idxi[grow];
        const float4 ev = *(const float4*)(cb7 + (size_t)code * D_ + c4 * 4);
        const size_t g = (size_t)grow * D_ + c4 * 4;
        const float4 xv = *(const float4*)(x + g);
        const float4 qv = *(const float4*)(qout + g);
        const float4 nq = make_float4(qv.x + ev.x, qv.y + ev.y, qv.z + ev.z, qv.w + ev.w);
        *(float4*)(qout + g) = nq;
        const float rx = xv.x - nq.x, ry = xv.y - nq.y;
        const float rz = xv.z - nq.z, rw = xv.w - nq.w;
        lsum += rx * rx + ry * ry + rz * rz + rw * rw;
    }
    #pragma unroll
    for (int m = 32; m; m >>= 1) lsum += __shfl_xor(lsum, m);
    if ((tid & 63) == 0) red[tid >> 6] = lsum;
    __syncthreads();
    if (tid == 0)
        atomicAdd(loss, (red[0] + red[1] + red[2] + red[3]) * (BETA / (float)ND_));
}

// ===========================================================================
// Legacy fp32 path (round-1, used only if ws is too small)
// ===========================================================================
__global__ __launch_bounds__(256) void k_init(float* __restrict__ qout,
                                              float* __restrict__ loss) {
    const size_t tid = (size_t)blockIdx.x * blockDim.x + threadIdx.x;
    float4* q4 = (float4*)qout;
    const size_t n4 = ND_ / 4;
    for (size_t i = tid; i < n4; i += (size_t)gridDim.x * blockDim.x)
        q4[i] = make_float4(0.f, 0.f, 0.f, 0.f);
    if (tid == 0) *loss = 0.f;
}

__global__ __launch_bounds__(256) void k_stage(const float* __restrict__ x,
                                               const float* __restrict__ cb,
                                               const float* __restrict__ enorm,
                                               float* __restrict__ qout,
                                               float* __restrict__ idxf,
                                               float* __restrict__ loss) {
    __shared__ float As[16][68];
    __shared__ float Bs[16][68];
    __shared__ int   sidx[64];
    __shared__ float red[4];
    const int tid = threadIdx.x;
    const int ty  = tid >> 4;
    const int tx  = tid & 15;
    const int rbase = blockIdx.x * 64;
    const int lrow = tid >> 2;
    const int ld4  = tid & 3;
    float minv[4]; int mini[4];
    #pragma unroll
    for (int i = 0; i < 4; ++i) { minv[i] = 3.4e38f; mini[i] = 0; }
    for (int cchunk = 0; cchunk < 16; ++cchunk) {
        const int cbase = cchunk * 64;
        float acc[4][4] = {};
        for (int kb = 0; kb < D_; kb += 16) {
            __syncthreads();
            {
                const size_t g = (size_t)(rbase + lrow) * D_ + kb + ld4 * 4;
                const float4 xv = *(const float4*)(x + g);
                const float4 qv = *(const float4*)(qout + g);
                As[ld4*4+0][lrow] = xv.x - qv.x; As[ld4*4+1][lrow] = xv.y - qv.y;
                As[ld4*4+2][lrow] = xv.z - qv.z; As[ld4*4+3][lrow] = xv.w - qv.w;
                const size_t gb = (size_t)(cbase + lrow) * D_ + kb + ld4 * 4;
                const float4 bv = *(const float4*)(cb + gb);
                Bs[ld4*4+0][lrow] = bv.x; Bs[ld4*4+1][lrow] = bv.y;
                Bs[ld4*4+2][lrow] = bv.z; Bs[ld4*4+3][lrow] = bv.w;
            }
            __syncthreads();
            #pragma unroll
            for (int kk = 0; kk < 16; ++kk) {
                const float4 av = *(const float4*)&As[kk][ty * 4];
                const float4 bv = *(const float4*)&Bs[kk][tx * 4];
                const float a[4] = {av.x, av.y, av.z, av.w};
                const float b[4] = {bv.x, bv.y, bv.z, bv.w};
                #pragma unroll
                for (int i = 0; i < 4; ++i)
                    #pragma unroll
                    for (int j = 0; j < 4; ++j)
                        acc[i][j] = fmaf(a[i], b[j], acc[i][j]);
            }
        }
        #pragma unroll
        for (int j = 0; j < 4; ++j) {
            const int c = cbase + tx * 4 + j;
            const float en = enorm[c];
            #pragma unroll
            for (int i = 0; i < 4; ++i) {
                const float s = fmaf(-2.f, acc[i][j], en);
                if (s < minv[i]) { minv[i] = s; mini[i] = c; }
            }
        }
    }
    #pragma unroll
    for (int i = 0; i < 4; ++i) {
        float v = minv[i]; int id = mini[i];
        #pragma unroll
        for (int m = 1; m < 16; m <<= 1) {
            const float ov = __shfl_xor(v, m); const int oid = __shfl_xor(id, m);
            if (ov < v || (ov == v && oid < id)) { v = ov; id = oid; }
        }
        if (tx == 0) sidx[ty * 4 + i] = id;
    }
    __syncthreads();
    if (tid < 64) idxf[rbase + tid] = (float)sidx[tid];
    float lsum = 0.f;
    #pragma unroll 4
    for (int k = 0; k < 32; ++k) {
        const int fidx = tid + k * 256;
        const int row = fidx >> 7, c4 = fidx & 127;
        const int code = sidx[row];
        const float4 qv = *(const float4*)(cb + (size_t)code * D_ + c4 * 4);
        const size_t g = (size_t)(rbase + row) * D_ + c4 * 4;
        const float4 xv = *(const float4*)(x + g);
        const float4 ov = *(const float4*)(qout + g);
        const float4 nq = make_float4(ov.x + qv.x, ov.y + qv.y, ov.z + qv.z, ov.w + qv.w);
        *(float4*)(qout + g) = nq;
        const float rx = xv.x - nq.x, ry = xv.y - nq.y;
        const float rz = xv.z - nq.z, rw = xv.w - nq.w;
        lsum += rx * rx + ry * ry + rz * rz + rw * rw;
    }
    #pragma unroll
    for (int m = 32; m; m >>= 1) lsum += __shfl_xor(lsum, m);
    if ((tid & 63) == 0) red[tid >> 6] = lsum;
    __syncthreads();
    if (tid == 0)
        atomicAdd(loss, (red[0] + red[1] + red[2] + red[3]) * (BETA / (float)ND_));
}

// ===========================================================================
extern "C" void kernel_launch(void* const* d_in, const int* in_sizes, int n_in,
                              void* d_out, int out_size, void* d_ws, size_t ws_size,
                              hipStream_t stream) {
    const float* x  = (const float*)d_in[0];   // [16,2048,512]
    const float* cb = (const float*)d_in[1];   // [8,1024,512]

    float* out  = (float*)d_out;
    float* qout = out;
    float* idxf = out + (size_t)ND_;
    float* loss = out + (size_t)ND_ + (size_t)Q_ * M_;

    if (ws_size >= WS_NEED) {
        char*  ws    = (char*)d_ws;
        short* cb16  = (short*)(ws + WS_CB16);
        float* enorm = (float*)(ws + WS_ENORM);
        int*   idxi  = (int*)(ws + WS_IDXI);
        int*   flags = (int*)(ws + WS_FLAGS);
        int*   cnt   = (int*)(ws + WS_CNT);

        hipLaunchKernelGGL(k_zero, dim3(1), dim3(64), 0, stream, loss, cnt);
        hipLaunchKernelGGL(k_cvt, dim3(2048), dim3(256), 0, stream, cb, cb16);
        hipLaunchKernelGGL(k_enorm, dim3((Q_ * C_) / 4), dim3(256), 0, stream, cb, enorm);

        for (int q = 0; q < Q_; ++q) {
            hipLaunchKernelGGL(k_approx, dim3(M_ / 128), dim3(512), 0, stream,
                               x,
                               cb + (size_t)(q > 0 ? q - 1 : 0) * C_ * D_,
                               cb16 + (size_t)q * C_ * D_,
                               enorm + (size_t)q * C_,
                               qout, idxi,
                               idxf + (size_t)q * M_,
                               flags, cnt + q, loss, q);
            hipLaunchKernelGGL(k_exact, dim3(128), dim3(256), 0, stream,
                               x, qout,
                               cb + (size_t)q * C_ * D_,
                               enorm + (size_t)q * C_,
                               idxi,
                               idxf + (size_t)q * M_,
                               flags, cnt + q, q > 0 ? 1 : 0);
        }
        hipLaunchKernelGGL(k_final, dim3(M_ / 64), dim3(256), 0, stream,
                           x, cb + (size_t)(Q_ - 1) * C_ * D_, idxi, qout, loss);
    } else {
        // legacy fp32 path
        float* enorm = (float*)d_ws;
        hipLaunchKernelGGL(k_init, dim3(4096), dim3(256), 0, stream, qout, loss);
        hipLaunchKernelGGL(k_enorm, dim3((Q_ * C_) / 4), dim3(256), 0, stream, cb, enorm);
        for (int q = 0; q < Q_; ++q) {
            hipLaunchKernelGGL(k_stage, dim3(M_ / 64), dim3(256), 0, stream,
                               x, cb + (size_t)q * C_ * D_, enorm + (size_t)q * C_,
                               qout, idxf + (size_t)q * M_, loss);
        }
    }
}